// Round 1
// baseline (101.275 us; speedup 1.0000x reference)
//
#include <hip/hip_runtime.h>
#include <math.h>

// Problem constants (from reference): B=32, L=2048, F=512, K=128, LOUT=1921
#define BB 32
#define LL 2048
#define FF 512
#define KK 128
#define LOUT (LL - KK + 1)      // 1921
#define NCHUNK 16
#define TCHUNK ((LOUT + NCHUNK - 1) / NCHUNK)  // 121

// ---------------------------------------------------------------------------
// Kernel 1: tau[b,f] = sigmoid((x[b,L-1,:] . W[f,:] + bias[f]) / 10 - 3)
//           norm[b,f] = 1 / sum_{i=0..K-1} tau^i   (Horner sum)
//           tauK[b,f] = tau^K                       (7 squarings, K=128)
// One block per b, 512 threads = one f each. feat row staged in LDS
// (broadcast reads, conflict-free).
// ---------------------------------------------------------------------------
__global__ __launch_bounds__(FF) void tau_kernel(const float* __restrict__ x,
                                                 const float* __restrict__ W,
                                                 const float* __restrict__ bias,
                                                 float* __restrict__ tau_out,
                                                 float* __restrict__ norm_out,
                                                 float* __restrict__ tauK_out) {
    __shared__ float feat[FF];
    const int b = blockIdx.x;
    const int f = threadIdx.x;
    feat[f] = x[((size_t)b * LL + (LL - 1)) * FF + f];
    __syncthreads();

    const float4* __restrict__ Wrow = (const float4*)(W + (size_t)f * FF);
    const float4* __restrict__ fv   = (const float4*)feat;
    float acc = 0.0f;
#pragma unroll 8
    for (int j = 0; j < FF / 4; ++j) {
        float4 w4 = Wrow[j];
        float4 x4 = fv[j];   // same addr across lanes -> LDS broadcast (free)
        acc = fmaf(w4.x, x4.x, acc);
        acc = fmaf(w4.y, x4.y, acc);
        acc = fmaf(w4.z, x4.z, acc);
        acc = fmaf(w4.w, x4.w, acc);
    }
    const float z   = (acc + bias[f]) * 0.1f - 3.0f;
    const float tau = 1.0f / (1.0f + expf(-z));

    // den = 1 + tau + ... + tau^(K-1), Horner (matches reference f32 sum ~1ulp)
    float den = 1.0f;
#pragma unroll 8
    for (int i = 0; i < KK - 1; ++i) den = fmaf(den, tau, 1.0f);

    // tau^128 via repeated squaring (underflows to 0 for this data's tau~0.05)
    float tk = tau;
#pragma unroll
    for (int i = 0; i < 7; ++i) tk *= tk;

    const int idx = b * FF + f;
    tau_out[idx]  = tau;
    norm_out[idx] = 1.0f / den;
    tauK_out[idx] = tk;
}

// ---------------------------------------------------------------------------
// Kernel 2: per-(b, time-chunk) block; 512 threads = all features.
//   warm-up:  S = sum_{i=0..K-1} tau^{K-1-i} x[t0+i]   (Horner, 128 FMAs)
//   steady:   S = tau*S + x[t+K-1] - tau^K * x[t-1];  out[t] = norm*S
// Fast path drops the tau^K term when it is exactly 0 for the whole wave.
// All global accesses coalesced across f (row-contiguous).
// ---------------------------------------------------------------------------
__global__ __launch_bounds__(FF) void fir_kernel(const float* __restrict__ x,
                                                 const float* __restrict__ tau_arr,
                                                 const float* __restrict__ norm_arr,
                                                 const float* __restrict__ tauK_arr,
                                                 float* __restrict__ out) {
    const int b = blockIdx.x / NCHUNK;
    const int c = blockIdx.x % NCHUNK;
    const int f = threadIdx.x;
    const int t0 = c * TCHUNK;
    const int tend = (t0 + TCHUNK < LOUT) ? (t0 + TCHUNK) : LOUT;

    const int idx = b * FF + f;
    const float tau  = tau_arr[idx];
    const float norm = norm_arr[idx];
    const float tauK = tauK_arr[idx];

    const float* __restrict__ xb = x + (size_t)b * LL * FF + f;
    float* __restrict__ ob = out + (size_t)b * LOUT * FF + f;

    // ---- warm-up Horner over the first window of this chunk ----
    float S = 0.0f;
#pragma unroll 4
    for (int i = 0; i < KK; ++i) {
        S = fmaf(S, tau, xb[(size_t)(t0 + i) * FF]);
    }
    ob[(size_t)t0 * FF] = norm * S;

    if (__all(tauK == 0.0f)) {
        // pure IIR: the trailing-edge term tau^K * x[t-1] is exactly 0
#pragma unroll 4
        for (int t = t0 + 1; t < tend; ++t) {
            S = fmaf(S, tau, xb[(size_t)(t + KK - 1) * FF]);
            ob[(size_t)t * FF] = norm * S;
        }
    } else {
        // general sliding-window recurrence (correct for any tau)
#pragma unroll 2
        for (int t = t0 + 1; t < tend; ++t) {
            const float leading  = xb[(size_t)(t + KK - 1) * FF];
            const float trailing = xb[(size_t)(t - 1) * FF];
            S = fmaf(S, tau, fmaf(-tauK, trailing, leading));
            ob[(size_t)t * FF] = norm * S;
        }
    }
}

extern "C" void kernel_launch(void* const* d_in, const int* in_sizes, int n_in,
                              void* d_out, int out_size, void* d_ws, size_t ws_size,
                              hipStream_t stream) {
    const float* x    = (const float*)d_in[0];  // [B, L, F]
    const float* W    = (const float*)d_in[1];  // [F, F]
    const float* bias = (const float*)d_in[2];  // [F]
    float* out = (float*)d_out;                 // [B, LOUT, F]

    float* ws = (float*)d_ws;
    float* tau_arr  = ws;                 // [B*F]
    float* norm_arr = ws + BB * FF;       // [B*F]
    float* tauK_arr = ws + 2 * BB * FF;   // [B*F]

    tau_kernel<<<BB, FF, 0, stream>>>(x, W, bias, tau_arr, norm_arr, tauK_arr);
    fir_kernel<<<BB * NCHUNK, FF, 0, stream>>>(x, tau_arr, norm_arr, tauK_arr, out);
}

// Round 2
// 63.718 us; speedup vs baseline: 1.5894x; 1.5894x over previous
//
#include <hip/hip_runtime.h>
#include <math.h>

// Problem constants: B=32, L=2048, F=512, K=128, LOUT=1921
#define BB 32
#define LL 2048
#define FF 512
#define KK 128
#define LOUT (LL - KK + 1)      // 1921
#define NCHUNK 64
#define TCHUNK ((LOUT + NCHUNK - 1) / NCHUNK)  // 31
#define F4 (FF / 4)             // 128

// ---------------------------------------------------------------------------
// Kernel 1: tau[b,f] = sigmoid((x[b,L-1,:] . W[f,:] + bias[f]) / 10 - 3)
//           norm[b,f] = 1 / sum_{i=0..K-1} tau^i   (Horner)
//           tauK[b,f] = tau^K                       (7 squarings)
// Grid = B*4 blocks of 128 threads; block (b, fq) computes f = fq*128+tid.
// feat row staged in LDS (broadcast reads). W rows read via float4.
// ---------------------------------------------------------------------------
__global__ __launch_bounds__(128) void tau_kernel(const float* __restrict__ x,
                                                  const float* __restrict__ W,
                                                  const float* __restrict__ bias,
                                                  float* __restrict__ tau_out,
                                                  float* __restrict__ norm_out,
                                                  float* __restrict__ tauK_out) {
    __shared__ float feat[FF];
    const int b   = blockIdx.x >> 2;
    const int fq  = blockIdx.x & 3;
    const int tid = threadIdx.x;

    ((float4*)feat)[tid] =
        ((const float4*)(x + ((size_t)b * LL + (LL - 1)) * FF))[tid];
    __syncthreads();

    const int f = fq * 128 + tid;
    const float4* __restrict__ Wrow = (const float4*)(W + (size_t)f * FF);
    const float4* __restrict__ fv   = (const float4*)feat;

    float a0 = 0.f, a1 = 0.f, a2 = 0.f, a3 = 0.f;  // 4 indep accumulators
#pragma unroll 4
    for (int j = 0; j < F4; j += 2) {
        float4 w0 = Wrow[j],     w1 = Wrow[j + 1];
        float4 x0 = fv[j],       x1 = fv[j + 1];
        a0 = fmaf(w0.x, x0.x, a0); a1 = fmaf(w0.y, x0.y, a1);
        a2 = fmaf(w0.z, x0.z, a2); a3 = fmaf(w0.w, x0.w, a3);
        a0 = fmaf(w1.x, x1.x, a0); a1 = fmaf(w1.y, x1.y, a1);
        a2 = fmaf(w1.z, x1.z, a2); a3 = fmaf(w1.w, x1.w, a3);
    }
    const float acc = (a0 + a1) + (a2 + a3);
    const float z   = (acc + bias[f]) * 0.1f - 3.0f;
    const float tau = 1.0f / (1.0f + expf(-z));

    float den = 1.0f;
#pragma unroll 8
    for (int i = 0; i < KK - 1; ++i) den = fmaf(den, tau, 1.0f);

    float tk = tau;
#pragma unroll
    for (int i = 0; i < 7; ++i) tk *= tk;

    const int idx = b * FF + f;
    tau_out[idx]  = tau;
    norm_out[idx] = 1.0f / den;
    tauK_out[idx] = tk;
}

// ---------------------------------------------------------------------------
// Kernel 2: per-(b, time-chunk) block; 128 threads, float4 across F
// (4 independent recurrences/thread -> 4x ILP on the dependent chain,
//  1 KiB per wave-load).
//   warm-up:  Horner over the last T taps of the first window, where
//             T = ceil(ln 1e-14 / ln tau_max) clamped to [4,K] -- taps
//             beyond T contribute < 1e-13 (exact full-K when tau -> 1).
//   steady:   S = tau*S + x[t+K-1] (- tau^K * x[t-1] in the general path);
//             out[t] = norm*S
// ---------------------------------------------------------------------------
__global__ __launch_bounds__(128) void fir_kernel(const float* __restrict__ x,
                                                  const float* __restrict__ tau_arr,
                                                  const float* __restrict__ norm_arr,
                                                  const float* __restrict__ tauK_arr,
                                                  float* __restrict__ out) {
    const int b  = blockIdx.x / NCHUNK;
    const int c  = blockIdx.x % NCHUNK;
    const int f4 = threadIdx.x;
    const int t0 = c * TCHUNK;
    if (t0 >= LOUT) return;
    const int tend = (t0 + TCHUNK < LOUT) ? (t0 + TCHUNK) : LOUT;

    const int idx4 = b * F4 + f4;
    const float4 tau = ((const float4*)tau_arr)[idx4];
    const float4 nrm = ((const float4*)norm_arr)[idx4];
    const float4 tk  = ((const float4*)tauK_arr)[idx4];

    const float4* __restrict__ xb = (const float4*)(x + (size_t)b * LL * FF) + f4;
    float4* __restrict__ ob = (float4*)(out + (size_t)b * LOUT * FF) + f4;

    // dynamic truncation length (wave-correct for any tau)
    const float tmax = fmaxf(fmaxf(tau.x, tau.y), fmaxf(tau.z, tau.w));
    int T = KK;
    if (tmax < 0.999f) {
        T = (int)ceilf(-32.236191f / logf(tmax));  // ln(1e-14) = -32.2362
        T = (T > KK) ? KK : (T < 4 ? 4 : T);
    }

    float4 S = make_float4(0.f, 0.f, 0.f, 0.f);
#pragma unroll 4
    for (int i = KK - T; i < KK; ++i) {
        const float4 v = xb[(size_t)(t0 + i) * F4];
        S.x = fmaf(S.x, tau.x, v.x);
        S.y = fmaf(S.y, tau.y, v.y);
        S.z = fmaf(S.z, tau.z, v.z);
        S.w = fmaf(S.w, tau.w, v.w);
    }
    ob[(size_t)t0 * F4] =
        make_float4(nrm.x * S.x, nrm.y * S.y, nrm.z * S.z, nrm.w * S.w);

    const bool fast =
        __all(tk.x == 0.f && tk.y == 0.f && tk.z == 0.f && tk.w == 0.f);

    if (fast) {
#pragma unroll 4
        for (int t = t0 + 1; t < tend; ++t) {
            const float4 v = xb[(size_t)(t + KK - 1) * F4];
            S.x = fmaf(S.x, tau.x, v.x);
            S.y = fmaf(S.y, tau.y, v.y);
            S.z = fmaf(S.z, tau.z, v.z);
            S.w = fmaf(S.w, tau.w, v.w);
            ob[(size_t)t * F4] =
                make_float4(nrm.x * S.x, nrm.y * S.y, nrm.z * S.z, nrm.w * S.w);
        }
    } else {
#pragma unroll 2
        for (int t = t0 + 1; t < tend; ++t) {
            const float4 lead  = xb[(size_t)(t + KK - 1) * F4];
            const float4 trail = xb[(size_t)(t - 1) * F4];
            S.x = fmaf(S.x, tau.x, fmaf(-tk.x, trail.x, lead.x));
            S.y = fmaf(S.y, tau.y, fmaf(-tk.y, trail.y, lead.y));
            S.z = fmaf(S.z, tau.z, fmaf(-tk.z, trail.z, lead.z));
            S.w = fmaf(S.w, tau.w, fmaf(-tk.w, trail.w, lead.w));
            ob[(size_t)t * F4] =
                make_float4(nrm.x * S.x, nrm.y * S.y, nrm.z * S.z, nrm.w * S.w);
        }
    }
}

extern "C" void kernel_launch(void* const* d_in, const int* in_sizes, int n_in,
                              void* d_out, int out_size, void* d_ws, size_t ws_size,
                              hipStream_t stream) {
    const float* x    = (const float*)d_in[0];  // [B, L, F]
    const float* W    = (const float*)d_in[1];  // [F, F]
    const float* bias = (const float*)d_in[2];  // [F]
    float* out = (float*)d_out;                 // [B, LOUT, F]

    float* ws = (float*)d_ws;
    float* tau_arr  = ws;                 // [B*F]
    float* norm_arr = ws + BB * FF;       // [B*F]
    float* tauK_arr = ws + 2 * BB * FF;   // [B*F]

    tau_kernel<<<BB * 4, 128, 0, stream>>>(x, W, bias, tau_arr, norm_arr, tauK_arr);
    fir_kernel<<<BB * NCHUNK, 128, 0, stream>>>(x, tau_arr, norm_arr, tauK_arr, out);
}